// Round 6
// baseline (272.225 us; speedup 1.0000x reference)
//
#include <hip/hip_runtime.h>

// ws layout: NBLK rows of ROW floats each:
//   [0]=cls  [1]=noobj  [2]=S0  [3]=S1_p0  [4]=S2_p0  [5]=S1_p1  [6]=S2_p1
//   [7]=reg_p0  [8]=reg_p1  [9]=imax (int bitcast)  [10..11] pad
#define NQ      9
#define ROW     12
#define NBLK    2048

// Segment-minimal design: pred is viewed as float2 (30 floats = 15 cell-aligned
// pairs). Each wave owns a 64-cell group and sweeps its pred as a PERFECTLY
// DENSE float2 stream (15 iters x 64 lanes x 8B = 512B/instr, every 64B segment
// 100% useful). Per element decode k = idx%15:
//   k>=5 -> cls pair, tcls float2 at cell*20+2k-10 (aggregate-dense monotonic:
//           every tcls byte read exactly once, near-segment-optimal)
//   k<5  -> box/conf pairs; obj/tbox via tiny in-branch loads (1.25KB per
//           64-cell group, L1-resident across the 15 iterations)
// Total L1<->L2 segment traffic ~= logical bytes (176MB), ~2.7x less than R5.
// No LDS staging, no hot-loop barriers, waves fully independent.
__global__ __launch_bounds__(256, 8) void yolo_partial_kernel(
    const float* __restrict__ pred,
    const float* __restrict__ tbox,
    const float* __restrict__ tcls,
    const int*   __restrict__ obj,
    float* __restrict__ partial,     // [gridDim.x * ROW]
    int M)
{
    const int t    = threadIdx.x;
    const int lane = t & 63;
    const int wid  = t >> 6;

    float acc[NQ];
#pragma unroll
    for (int q = 0; q < NQ; ++q) acc[q] = 0.f;
    int imax = -1;

    const int ngrp = M >> 6;                   // full 64-cell wave-groups
    const float2* pf2 = reinterpret_cast<const float2*>(pred);

    for (int g = blockIdx.x * 4 + wid; g < ngrp; g += gridDim.x * 4) {
        const int    cbase = g << 6;           // first cell of this group
        const size_t fbase = (size_t)g * 960;  // float2 base (64 cells * 15)

        for (int j = 0; j < 15; ++j) {
            const int idx = j * 64 + lane;     // 0..959, dense across the wave
            const float2 v = pf2[fbase + idx];
            const unsigned cl = (unsigned)idx / 15u;   // local cell 0..63
            const int k = idx - (int)cl * 15;          // pair index 0..14
            const int cell = cbase + (int)cl;

            if (k >= 5) {
                // cls pair: channels (2k-10, 2k-9)
                const float2 tc = *reinterpret_cast<const float2*>(
                    tcls + (size_t)cell * 20 + (2 * k - 10));
                float d0 = v.x - tc.x, d1 = v.y - tc.y;
                acc[0] += d0 * d0 + d1 * d1;
            } else {
                const int ov = obj[cell];
                const float* tbp = tbox + (size_t)cell * 4;
                if (k == 0) {                  // (x0, y0)
                    if (ov) {
                        float d0 = v.x - tbp[0], d1 = v.y - tbp[1];
                        acc[7] += d0 * d0 + d1 * d1;
                    }
                } else if (k == 1) {           // (w0, h0)
                    if (ov) {
                        float d0 = sqrtf(v.x) - sqrtf(tbp[2]);
                        float d1 = sqrtf(v.y) - sqrtf(tbp[3]);
                        acc[7] += d0 * d0 + d1 * d1;
                    }
                } else if (k == 2) {           // (c0, x1)
                    if (!ov) {
                        acc[1] += v.x * v.x;   // L_NOOBJ * 2 == 1.0
                    } else {
                        acc[2] += 1.f;
                        acc[3] += v.x;  acc[4] += v.x * v.x;
                        float d = v.y - tbp[0];
                        acc[8] += d * d;
                        imax = cell;
                    }
                } else if (k == 3) {           // (y1, w1)
                    if (ov) {
                        float d0 = v.x - tbp[1];
                        float d1 = sqrtf(v.y) - sqrtf(tbp[2]);
                        acc[8] += d0 * d0 + d1 * d1;
                    }
                } else {                       // k == 4: (h1, c1)
                    if (ov) {
                        float d0 = sqrtf(v.x) - sqrtf(tbp[3]);
                        acc[8] += d0 * d0;
                        acc[5] += v.y;  acc[6] += v.y * v.y;
                    }
                }
            }
        }
    }

    // ---- tail cells (only if M % 64 != 0): scalar, correctness-only ----
    const int rem = M - (ngrp << 6);
    if (rem > 0 && blockIdx.x == 0 && wid == 0 && lane < rem) {
        const int cell = (ngrp << 6) + lane;
        const float* p   = pred + (size_t)cell * 30;
        const float* tcl = tcls + (size_t)cell * 20;
#pragma unroll
        for (int ch = 0; ch < 20; ++ch) {
            float d = p[10 + ch] - tcl[ch];
            acc[0] += d * d;
        }
        const int ov = obj[cell];
        const float p0c = p[4], p1c = p[9];
        if (ov == 0) {
            acc[1] += p0c * p0c;
        } else {
            const float* tb = tbox + (size_t)cell * 4;
            acc[2] += 1.f;
            acc[3] += p0c;  acc[4] += p0c * p0c;
            acc[5] += p1c;  acc[6] += p1c * p1c;
            const float st2 = sqrtf(tb[2]), st3 = sqrtf(tb[3]);
            float dx = p[0] - tb[0], dy = p[1] - tb[1];
            float dw = sqrtf(p[2]) - st2, dh = sqrtf(p[3]) - st3;
            acc[7] += dx * dx + dy * dy + dw * dw + dh * dh;
            dx = p[5] - tb[0]; dy = p[6] - tb[1];
            dw = sqrtf(p[7]) - st2; dh = sqrtf(p[8]) - st3;
            acc[8] += dx * dx + dy * dy + dw * dw + dh * dh;
            imax = cell;
        }
    }

    // ---- wave (64-lane) shuffle reduction ----
#pragma unroll
    for (int off = 32; off > 0; off >>= 1) {
#pragma unroll
        for (int q = 0; q < NQ; ++q) acc[q] += __shfl_down(acc[q], off, 64);
        imax = max(imax, __shfl_down(imax, off, 64));
    }

    __shared__ float sred[4][NQ];
    __shared__ int   sidx[4];
    if (lane == 0) {
#pragma unroll
        for (int q = 0; q < NQ; ++q) sred[wid][q] = acc[q];
        sidx[wid] = imax;
    }
    __syncthreads();

    if (t == 0) {
        float tot[NQ];
        int   mx = sidx[0];
#pragma unroll
        for (int q = 0; q < NQ; ++q) tot[q] = sred[0][q];
        for (int w = 1; w < 4; ++w) {
#pragma unroll
            for (int q = 0; q < NQ; ++q) tot[q] += sred[w][q];
            mx = max(mx, sidx[w]);
        }
        float* row = partial + (size_t)blockIdx.x * ROW;
#pragma unroll
        for (int q = 0; q < NQ; ++q) row[q] = tot[q];
        reinterpret_cast<int*>(row)[NQ] = mx;
    }
}

__global__ __launch_bounds__(256) void yolo_final_kernel(
    const float* __restrict__ pred,
    const float* __restrict__ tbox,
    const float* __restrict__ partial,
    float* __restrict__ out,
    int nrows, float invN)
{
    const int t = threadIdx.x;
    float acc[NQ];
#pragma unroll
    for (int q = 0; q < NQ; ++q) acc[q] = 0.f;
    int imax = -1;

    for (int r = t; r < nrows; r += 256) {
        const float* row = partial + (size_t)r * ROW;
#pragma unroll
        for (int q = 0; q < NQ; ++q) acc[q] += row[q];
        imax = max(imax, reinterpret_cast<const int*>(row)[NQ]);
    }

#pragma unroll
    for (int off = 32; off > 0; off >>= 1) {
#pragma unroll
        for (int q = 0; q < NQ; ++q) acc[q] += __shfl_down(acc[q], off, 64);
        imax = max(imax, __shfl_down(imax, off, 64));
    }

    __shared__ float sred[4][NQ];
    __shared__ int   sidx[4];
    const int lane = t & 63;
    const int wid  = t >> 6;
    if (lane == 0) {
#pragma unroll
        for (int q = 0; q < NQ; ++q) sred[wid][q] = acc[q];
        sidx[wid] = imax;
    }
    __syncthreads();

    if (t == 0) {
        float sums[NQ];
        int idx = sidx[0];
#pragma unroll
        for (int q = 0; q < NQ; ++q) sums[q] = sred[0][q];
        for (int w = 1; w < 4; ++w) {
#pragma unroll
            for (int q = 0; q < NQ; ++q) sums[q] += sred[w][q];
            idx = max(idx, sidx[w]);
        }

        const float* p  = pred + (size_t)idx * 30;
        const float* tb = tbox + (size_t)idx * 4;

        float b0[4], b1[4], bt[4];
        {
            float cx = p[0] / 14.f, cy = p[1] / 14.f;
            b0[0] = cx - 0.5f * p[2]; b0[1] = cy - 0.5f * p[3];
            b0[2] = cx + 0.5f * p[2]; b0[3] = cy + 0.5f * p[3];
        }
        {
            float cx = p[5] / 14.f, cy = p[6] / 14.f;
            b1[0] = cx - 0.5f * p[7]; b1[1] = cy - 0.5f * p[8];
            b1[2] = cx + 0.5f * p[7]; b1[3] = cy + 0.5f * p[8];
        }
        {
            float cx = tb[0] / 14.f, cy = tb[1] / 14.f;
            bt[0] = cx - 0.5f * tb[2]; bt[1] = cy - 0.5f * tb[3];
            bt[2] = cx + 0.5f * tb[2]; bt[3] = cy + 0.5f * tb[3];
        }
        auto iou = [](const float* a, const float* b) {
            float ltx = fmaxf(a[0], b[0]), lty = fmaxf(a[1], b[1]);
            float rbx = fminf(a[2], b[2]), rby = fminf(a[3], b[3]);
            float w = fmaxf(rbx - ltx, 0.f), h = fmaxf(rby - lty, 0.f);
            float inter = w * h;
            float a1 = (a[2] - a[0]) * (a[3] - a[1]);
            float a2 = (b[2] - b[0]) * (b[3] - b[1]);
            return inter / (a1 + a2 - inter);
        };
        float iou0 = iou(b0, bt), iou1 = iou(b1, bt);
        bool  m = iou0 > iou1;
        float c = m ? iou0 : iou1;

        float S0  = sums[2];
        float S1  = m ? sums[3] : sums[5];
        float S2  = m ? sums[4] : sums[6];
        float reg = m ? sums[7] : sums[8];

        float reg_loss   = 5.f * reg;                       // L_COORD
        float containing = S2 - 2.f * c * S1 + c * c * S0;  // sum obj*(conf-c)^2
        float noobj      = sums[1];
        float cls        = sums[0];
        float total      = cls + noobj + reg_loss + containing;

        out[0] = total * invN;
        out[1] = reg_loss * invN;
        out[2] = containing * invN;
        out[3] = noobj * invN;
        out[4] = cls * invN;
    }
}

extern "C" void kernel_launch(void* const* d_in, const int* in_sizes, int n_in,
                              void* d_out, int out_size, void* d_ws, size_t ws_size,
                              hipStream_t stream) {
    const float* pred = (const float*)d_in[0];
    const float* tbox = (const float*)d_in[1];
    const float* tcls = (const float*)d_in[2];
    const int*   obj  = (const int*)d_in[3];
    float* out = (float*)d_out;

    const int M = in_sizes[3];                  // BATCH * S * S
    const int N = in_sizes[0] / (14 * 14 * 30); // BATCH

    int nblk = NBLK;
    const int max_rows = (int)(ws_size / (ROW * sizeof(float)));
    if (nblk > max_rows) nblk = max_rows;
    if (nblk < 1) nblk = 1;

    float* partial = (float*)d_ws;

    yolo_partial_kernel<<<nblk, 256, 0, stream>>>(pred, tbox, tcls, obj, partial, M);
    yolo_final_kernel<<<1, 256, 0, stream>>>(pred, tbox, partial, out, nblk, 1.f / (float)N);
}